// Round 9
// baseline (64.911 us; speedup 1.0000x reference)
//
#include <hip/hip_runtime.h>
#include <math.h>

#define RR 8192
#define FF 4096
#define LL 2048
#define NBLK 1024          // gemv blocks: 8 waves, wave-per-row
#define TPB 512

// ws layout (floats): w1[FF] | w2[FF] | q | cnt | pad | partials[NBLK*3]
#define WS_W1  0
#define WS_W2  FF
#define WS_Q   (2 * FF)
#define WS_CNT (2 * FF + 4)
#define WS_P   (2 * FF + 16)

// ---------------- kernel 1: prep (2 blocks) — r8-verified ----------------
// block 0: w1 (k-weights) + q ;  block 1: w2 (v-weights) + ticket reset
__global__ __launch_bounds__(1024) void prep(const float* __restrict__ in,
                                             const int* __restrict__ idx,
                                             const float* __restrict__ wts,
                                             float* __restrict__ ws) {
    __shared__ float wsh[FF];
    __shared__ float qred[16];

    const int t = threadIdx.x, lane = t & 63, wv = t >> 6;
    const int b = blockIdx.x;

    for (int i = t; i < FF; i += 1024) wsh[i] = 0.f;
    __syncthreads();

    if (b == 0) {
        const float* lastrow = in + (size_t)(RR - 1) * FF;
        float qp = 0.f;
#pragma unroll
        for (int l = t; l < LL; l += 1024) {
            const int c = idx[l];
            qp += lastrow[c] * wts[3 * l + 0];
            atomicAdd(&wsh[c], wts[3 * l + 1]);
        }
        for (int o = 32; o > 0; o >>= 1) qp += __shfl_down(qp, o);
        if (lane == 0) qred[wv] = qp;
        __syncthreads();
        if (t < FF / 4)
            *(float4*)(ws + WS_W1 + t * 4) = *(const float4*)&wsh[t * 4];
        if (t == 0) {
            float q = 0.f;
#pragma unroll
            for (int i = 0; i < 16; ++i) q += qred[i];
            ws[WS_Q] = q;
        }
    } else {
#pragma unroll
        for (int l = t; l < LL; l += 1024) {
            atomicAdd(&wsh[idx[l]], wts[3 * l + 2]);
        }
        __syncthreads();
        if (t < FF / 4)
            *(float4*)(ws + WS_W2 + t * 4) = *(const float4*)&wsh[t * 4];
        if (t == 0)
            *((unsigned int*)(ws + WS_CNT)) = 0u;   // reset ticket every call
    }
}

// ---------------- kernel 2: r3 gemv engine + ticket combine tail ----------------
__global__ __launch_bounds__(TPB) void gemv_combine(const float* __restrict__ in,
                                                    float* __restrict__ ws,
                                                    float* __restrict__ out) {
    const int t = threadIdx.x, lane = t & 63, wv = t >> 6;
    const int row = blockIdx.x * 8 + wv;
    const float* __restrict__ x  = in + (size_t)row * FF;
    const float* __restrict__ w1 = ws + WS_W1;
    const float* __restrict__ w2 = ws + WS_W2;

    float k = 0.f, v = 0.f;
#pragma unroll
    for (int i = 0; i < FF; i += 256) {          // 16 float4 per lane, r3 schedule
        const int c = i + lane * 4;
        const float4 xv = *(const float4*)(x + c);
        const float4 a1 = *(const float4*)(w1 + c);
        const float4 a2 = *(const float4*)(w2 + c);
        k += xv.x * a1.x + xv.y * a1.y + xv.z * a1.z + xv.w * a1.w;
        v += xv.x * a2.x + xv.y * a2.y + xv.z * a2.z + xv.w * a2.w;
    }
    for (int o = 32; o > 0; o >>= 1) { k += __shfl_down(k, o); v += __shfl_down(v, o); }

    __shared__ float kv[8][2];
    __shared__ int lastFlag;
    __shared__ float red[8], red2[8], red3[8], bc[1];
    if (lane == 0) { kv[wv][0] = k; kv[wv][1] = v; }
    __syncthreads();

    if (t == 0) {
        const float q = ws[WS_Q];
        float m = -INFINITY;
#pragma unroll
        for (int r = 0; r < 8; ++r) m = fmaxf(m, q * kv[r][0]);
        float se = 0.f, sv = 0.f;
#pragma unroll
        for (int r = 0; r < 8; ++r) {
            const float e = expf(q * kv[r][0] - m);
            se += e;
            sv += e * kv[r][1];
        }
        float* p = ws + WS_P + blockIdx.x * 3;
        __hip_atomic_store(p + 0, m,  __ATOMIC_RELAXED, __HIP_MEMORY_SCOPE_AGENT);
        __hip_atomic_store(p + 1, se, __ATOMIC_RELAXED, __HIP_MEMORY_SCOPE_AGENT);
        __hip_atomic_store(p + 2, sv, __ATOMIC_RELAXED, __HIP_MEMORY_SCOPE_AGENT);
        __threadfence();
        const unsigned old = atomicAdd((unsigned int*)(ws + WS_CNT), 1u);
        lastFlag = (old == NBLK - 1) ? 1 : 0;
    }
    __syncthreads();
    if (!lastFlag) return;

    // ---- last-arriving block: merge 1024 partials -> sigmoid ----
    __threadfence();
    const float* __restrict__ P = ws + WS_P;
    float lm[NBLK / TPB], lse[NBLK / TPB], lsv[NBLK / TPB];
    float m = -INFINITY;
#pragma unroll
    for (int i = 0; i < NBLK / TPB; ++i) {
        const int b = t + i * TPB;
        lm[i]  = __hip_atomic_load(P + b * 3 + 0, __ATOMIC_RELAXED, __HIP_MEMORY_SCOPE_AGENT);
        lse[i] = __hip_atomic_load(P + b * 3 + 1, __ATOMIC_RELAXED, __HIP_MEMORY_SCOPE_AGENT);
        lsv[i] = __hip_atomic_load(P + b * 3 + 2, __ATOMIC_RELAXED, __HIP_MEMORY_SCOPE_AGENT);
        m = fmaxf(m, lm[i]);
    }
    for (int o = 32; o > 0; o >>= 1) m = fmaxf(m, __shfl_down(m, o));
    if (lane == 0) red[wv] = m;
    __syncthreads();
    if (t == 0) {
        float xx = red[0];
#pragma unroll
        for (int i = 1; i < 8; ++i) xx = fmaxf(xx, red[i]);
        bc[0] = xx;
    }
    __syncthreads();
    const float gm = bc[0];

    float se = 0.f, sv = 0.f;
#pragma unroll
    for (int i = 0; i < NBLK / TPB; ++i) {
        const float s = expf(lm[i] - gm);
        se += lse[i] * s;
        sv += lsv[i] * s;
    }
    for (int o = 32; o > 0; o >>= 1) { se += __shfl_down(se, o); sv += __shfl_down(sv, o); }
    if (lane == 0) { red2[wv] = se; red3[wv] = sv; }
    __syncthreads();
    if (t == 0) {
        float S = 0.f, V = 0.f;
#pragma unroll
        for (int i = 0; i < 8; ++i) { S += red2[i]; V += red3[i]; }
        out[0] = 1.0f / (1.0f + expf(-(V / S)));
    }
}

extern "C" void kernel_launch(void* const* d_in, const int* in_sizes, int n_in,
                              void* d_out, int out_size, void* d_ws, size_t ws_size,
                              hipStream_t stream) {
    const float* inputs = (const float*)d_in[0];
    const int*   idx    = (const int*)d_in[1];
    const float* wts    = (const float*)d_in[2];
    float* out = (float*)d_out;
    float* ws  = (float*)d_ws;

    prep<<<2, 1024, 0, stream>>>(inputs, idx, wts, ws);
    gemv_combine<<<NBLK, TPB, 0, stream>>>(inputs, ws, out);
}

// Round 10
// 34.955 us; speedup vs baseline: 1.8570x; 1.8570x over previous
//
#include <hip/hip_runtime.h>
#include <math.h>

#define RR 8192
#define FF 4096
#define LL 2048
#define NBLK 1024          // gemv blocks: 8 waves, wave-per-row
#define TPB 512

// ws layout (floats): w1[FF] | w2[FF] | q | pad | partials[NBLK*3]
#define WS_W1  0
#define WS_W2  FF
#define WS_Q   (2 * FF)
#define WS_P   (2 * FF + 16)

// ---------------- kernel 1: prep (2 blocks) — r8-verified ----------------
// block 0: w1 (k-weights) + q ;  block 1: w2 (v-weights)
__global__ __launch_bounds__(1024) void prep(const float* __restrict__ in,
                                             const int* __restrict__ idx,
                                             const float* __restrict__ wts,
                                             float* __restrict__ ws) {
    __shared__ float wsh[FF];
    __shared__ float qred[16];

    const int t = threadIdx.x, lane = t & 63, wv = t >> 6;
    const int b = blockIdx.x;

    for (int i = t; i < FF; i += 1024) wsh[i] = 0.f;
    __syncthreads();

    if (b == 0) {
        const float* lastrow = in + (size_t)(RR - 1) * FF;
        float qp = 0.f;
#pragma unroll
        for (int l = t; l < LL; l += 1024) {
            const int c = idx[l];
            qp += lastrow[c] * wts[3 * l + 0];
            atomicAdd(&wsh[c], wts[3 * l + 1]);
        }
        for (int o = 32; o > 0; o >>= 1) qp += __shfl_down(qp, o);
        if (lane == 0) qred[wv] = qp;
        __syncthreads();
        if (t < FF / 4)
            *(float4*)(ws + WS_W1 + t * 4) = *(const float4*)&wsh[t * 4];
        if (t == 0) {
            float q = 0.f;
#pragma unroll
            for (int i = 0; i < 16; ++i) q += qred[i];
            ws[WS_Q] = q;
        }
    } else {
#pragma unroll
        for (int l = t; l < LL; l += 1024) {
            atomicAdd(&wsh[idx[l]], wts[3 * l + 2]);
        }
        __syncthreads();
        if (t < FF / 4)
            *(float4*)(ws + WS_W2 + t * 4) = *(const float4*)&wsh[t * 4];
    }
}

// ---------------- kernel 2: wave-per-row GEMV, weights in LDS, NO fences/atomics ----------------
__global__ __launch_bounds__(TPB) void gemv_kv(const float* __restrict__ in,
                                               const float* __restrict__ ws,
                                               float* __restrict__ partials) {
    __shared__ float w1s[FF];          // 16 KB
    __shared__ float w2s[FF];          // 16 KB
    __shared__ float kv[8][2];

    const int t = threadIdx.x, lane = t & 63, wv = t >> 6;

    // stage weights into LDS (32 KB from L2/L3, coalesced float4)
    for (int i = t; i < FF / 4; i += TPB) {
        *(float4*)&w1s[i * 4] = *(const float4*)(ws + WS_W1 + i * 4);
        *(float4*)&w2s[i * 4] = *(const float4*)(ws + WS_W2 + i * 4);
    }
    __syncthreads();

    const int row = blockIdx.x * 8 + wv;
    const float* __restrict__ x = in + (size_t)row * FF;

    float k = 0.f, v = 0.f;
#pragma unroll
    for (int i = 0; i < FF; i += 256) {          // 16 iters: 1 global float4 + 2 LDS float4
        const int c = i + lane * 4;
        const float4 xv = *(const float4*)(x + c);
        const float4 a1 = *(const float4*)&w1s[c];
        const float4 a2 = *(const float4*)&w2s[c];
        k += xv.x * a1.x + xv.y * a1.y + xv.z * a1.z + xv.w * a1.w;
        v += xv.x * a2.x + xv.y * a2.y + xv.z * a2.z + xv.w * a2.w;
    }
    for (int o = 32; o > 0; o >>= 1) { k += __shfl_down(k, o); v += __shfl_down(v, o); }
    if (lane == 0) { kv[wv][0] = k; kv[wv][1] = v; }
    __syncthreads();

    if (t == 0) {
        const float q = ws[WS_Q];
        float m = -INFINITY;
#pragma unroll
        for (int r = 0; r < 8; ++r) m = fmaxf(m, q * kv[r][0]);
        float se = 0.f, sv = 0.f;
#pragma unroll
        for (int r = 0; r < 8; ++r) {
            const float e = expf(q * kv[r][0] - m);
            se += e;
            sv += e * kv[r][1];
        }
        partials[blockIdx.x * 3 + 0] = m;
        partials[blockIdx.x * 3 + 1] = se;
        partials[blockIdx.x * 3 + 2] = sv;
    }
}

// ---------------- kernel 3: merge 1024 partials -> sigmoid ----------------
__global__ __launch_bounds__(TPB) void combine(const float* __restrict__ partials,
                                               float* __restrict__ out) {
    const int t = threadIdx.x, lane = t & 63, wv = t >> 6;
    float lm[2], lse[2], lsv[2];
    float m = -INFINITY;
#pragma unroll
    for (int i = 0; i < 2; ++i) {
        const int b = t + i * TPB;
        lm[i]  = partials[b * 3 + 0];
        lse[i] = partials[b * 3 + 1];
        lsv[i] = partials[b * 3 + 2];
        m = fmaxf(m, lm[i]);
    }

    __shared__ float red[8], red2[8], red3[8], bc[1];
    for (int o = 32; o > 0; o >>= 1) m = fmaxf(m, __shfl_down(m, o));
    if (lane == 0) red[wv] = m;
    __syncthreads();
    if (t == 0) {
        float x = red[0];
#pragma unroll
        for (int i = 1; i < 8; ++i) x = fmaxf(x, red[i]);
        bc[0] = x;
    }
    __syncthreads();
    const float gm = bc[0];

    float se = 0.f, sv = 0.f;
#pragma unroll
    for (int i = 0; i < 2; ++i) {
        const float s = expf(lm[i] - gm);
        se += lse[i] * s;
        sv += lsv[i] * s;
    }
    for (int o = 32; o > 0; o >>= 1) { se += __shfl_down(se, o); sv += __shfl_down(sv, o); }
    if (lane == 0) { red2[wv] = se; red3[wv] = sv; }
    __syncthreads();
    if (t == 0) {
        float S = 0.f, V = 0.f;
#pragma unroll
        for (int i = 0; i < 8; ++i) { S += red2[i]; V += red3[i]; }
        out[0] = 1.0f / (1.0f + expf(-(V / S)));
    }
}

extern "C" void kernel_launch(void* const* d_in, const int* in_sizes, int n_in,
                              void* d_out, int out_size, void* d_ws, size_t ws_size,
                              hipStream_t stream) {
    const float* inputs = (const float*)d_in[0];
    const int*   idx    = (const int*)d_in[1];
    const float* wts    = (const float*)d_in[2];
    float* out = (float*)d_out;
    float* ws  = (float*)d_ws;

    prep<<<2, 1024, 0, stream>>>(inputs, idx, wts, ws);
    gemv_kv<<<NBLK, TPB, 0, stream>>>(inputs, ws, ws + WS_P);
    combine<<<1, TPB, 0, stream>>>(ws + WS_P, out);
}

// Round 11
// 34.077 us; speedup vs baseline: 1.9048x; 1.0258x over previous
//
#include <hip/hip_runtime.h>
#include <math.h>

#define RR 8192
#define FF 4096
#define LL 2048
#define NBLK 1024          // gemv blocks: 8 waves, wave-per-row
#define TPB 512

// ws layout (floats): w1[FF] | w2[FF] | q | pad | partials[NBLK*3]
#define WS_W1  0
#define WS_W2  FF
#define WS_Q   (2 * FF)
#define WS_P   (2 * FF + 16)

// ---------------- kernel 1: prep (2 blocks) — verified ----------------
__global__ __launch_bounds__(1024) void prep(const float* __restrict__ in,
                                             const int* __restrict__ idx,
                                             const float* __restrict__ wts,
                                             float* __restrict__ ws) {
    __shared__ float wsh[FF];
    __shared__ float qred[16];

    const int t = threadIdx.x, lane = t & 63, wv = t >> 6;
    const int b = blockIdx.x;

    for (int i = t; i < FF; i += 1024) wsh[i] = 0.f;
    __syncthreads();

    if (b == 0) {
        const float* lastrow = in + (size_t)(RR - 1) * FF;
        float qp = 0.f;
#pragma unroll
        for (int l = t; l < LL; l += 1024) {
            const int c = idx[l];
            qp += lastrow[c] * wts[3 * l + 0];
            atomicAdd(&wsh[c], wts[3 * l + 1]);
        }
        for (int o = 32; o > 0; o >>= 1) qp += __shfl_down(qp, o);
        if (lane == 0) qred[wv] = qp;
        __syncthreads();
        if (t < FF / 4)
            *(float4*)(ws + WS_W1 + t * 4) = *(const float4*)&wsh[t * 4];
        if (t == 0) {
            float q = 0.f;
#pragma unroll
            for (int i = 0; i < 16; ++i) q += qred[i];
            ws[WS_Q] = q;
        }
    } else {
#pragma unroll
        for (int l = t; l < LL; l += 1024) {
            atomicAdd(&wsh[idx[l]], wts[3 * l + 2]);
        }
        __syncthreads();
        if (t < FF / 4)
            *(float4*)(ws + WS_W2 + t * 4) = *(const float4*)&wsh[t * 4];
    }
}

// ---------------- kernel 2: wave-per-row GEMV, staging hidden under x-stream ----------------
__global__ __launch_bounds__(TPB, 8) void gemv_kv(const float* __restrict__ in,
                                                  const float* __restrict__ ws,
                                                  float* __restrict__ partials) {
    __shared__ float w1s[FF];          // 16 KB
    __shared__ float w2s[FF];          // 16 KB
    __shared__ float kv[8][2];

    const int t = threadIdx.x, lane = t & 63, wv = t >> 6;
    const int row = blockIdx.x * 8 + wv;
    const float* __restrict__ x = in + (size_t)row * FF;

    // hoist the q scalar (uniform) so the tail doesn't pay its latency
    const float q = ws[WS_Q];

    // ---- issue staging loads FIRST (L2-hot), keep them in regs ----
    const float4* __restrict__ wsrc1 = (const float4*)(ws + WS_W1);
    const float4* __restrict__ wsrc2 = (const float4*)(ws + WS_W2);
    const float4 s10 = wsrc1[t], s11 = wsrc1[512 + t];
    const float4 s20 = wsrc2[t], s21 = wsrc2[512 + t];

    // ---- chunks 0-3 with GLOBAL weight reads (same bits as LDS copy):
    //      the x HBM stream starts immediately, staging latency hides under it
    float k = 0.f, v = 0.f;
#pragma unroll
    for (int i = 0; i < 4; ++i) {
        const int c = i * 256 + lane * 4;
        const float4 xv = *(const float4*)(x + c);
        const float4 a1 = *(const float4*)(ws + WS_W1 + c);
        const float4 a2 = *(const float4*)(ws + WS_W2 + c);
        k += xv.x * a1.x + xv.y * a1.y + xv.z * a1.z + xv.w * a1.w;
        v += xv.x * a2.x + xv.y * a2.y + xv.z * a2.z + xv.w * a2.w;
    }

    // ---- commit staged weights to LDS, barrier ----
    ((float4*)w1s)[t] = s10; ((float4*)w1s)[512 + t] = s11;
    ((float4*)w2s)[t] = s20; ((float4*)w2s)[512 + t] = s21;
    __syncthreads();

    // ---- chunks 4-15 from LDS ----
#pragma unroll
    for (int i = 4; i < 16; ++i) {
        const int c = i * 256 + lane * 4;
        const float4 xv = *(const float4*)(x + c);
        const float4 a1 = *(const float4*)&w1s[c];
        const float4 a2 = *(const float4*)&w2s[c];
        k += xv.x * a1.x + xv.y * a1.y + xv.z * a1.z + xv.w * a1.w;
        v += xv.x * a2.x + xv.y * a2.y + xv.z * a2.z + xv.w * a2.w;
    }
    for (int o = 32; o > 0; o >>= 1) { k += __shfl_down(k, o); v += __shfl_down(v, o); }
    if (lane == 0) { kv[wv][0] = k; kv[wv][1] = v; }
    __syncthreads();

    if (t == 0) {
        float m = -INFINITY;
#pragma unroll
        for (int r = 0; r < 8; ++r) m = fmaxf(m, q * kv[r][0]);
        float se = 0.f, sv = 0.f;
#pragma unroll
        for (int r = 0; r < 8; ++r) {
            const float e = expf(q * kv[r][0] - m);
            se += e;
            sv += e * kv[r][1];
        }
        partials[blockIdx.x * 3 + 0] = m;
        partials[blockIdx.x * 3 + 1] = se;
        partials[blockIdx.x * 3 + 2] = sv;
    }
}

// ---------------- kernel 3: merge 1024 partials -> sigmoid ----------------
__global__ __launch_bounds__(TPB) void combine(const float* __restrict__ partials,
                                               float* __restrict__ out) {
    const int t = threadIdx.x, lane = t & 63, wv = t >> 6;
    float lm[2], lse[2], lsv[2];
    float m = -INFINITY;
#pragma unroll
    for (int i = 0; i < 2; ++i) {
        const int b = t + i * TPB;
        lm[i]  = partials[b * 3 + 0];
        lse[i] = partials[b * 3 + 1];
        lsv[i] = partials[b * 3 + 2];
        m = fmaxf(m, lm[i]);
    }

    __shared__ float red[8], red2[8], red3[8], bc[1];
    for (int o = 32; o > 0; o >>= 1) m = fmaxf(m, __shfl_down(m, o));
    if (lane == 0) red[wv] = m;
    __syncthreads();
    if (t == 0) {
        float x = red[0];
#pragma unroll
        for (int i = 1; i < 8; ++i) x = fmaxf(x, red[i]);
        bc[0] = x;
    }
    __syncthreads();
    const float gm = bc[0];

    float se = 0.f, sv = 0.f;
#pragma unroll
    for (int i = 0; i < 2; ++i) {
        const float s = expf(lm[i] - gm);
        se += lse[i] * s;
        sv += lsv[i] * s;
    }
    for (int o = 32; o > 0; o >>= 1) { se += __shfl_down(se, o); sv += __shfl_down(sv, o); }
    if (lane == 0) { red2[wv] = se; red3[wv] = sv; }
    __syncthreads();
    if (t == 0) {
        float S = 0.f, V = 0.f;
#pragma unroll
        for (int i = 0; i < 8; ++i) { S += red2[i]; V += red3[i]; }
        out[0] = 1.0f / (1.0f + expf(-(V / S)));
    }
}

extern "C" void kernel_launch(void* const* d_in, const int* in_sizes, int n_in,
                              void* d_out, int out_size, void* d_ws, size_t ws_size,
                              hipStream_t stream) {
    const float* inputs = (const float*)d_in[0];
    const int*   idx    = (const int*)d_in[1];
    const float* wts    = (const float*)d_in[2];
    float* out = (float*)d_out;
    float* ws  = (float*)d_ws;

    prep<<<2, 1024, 0, stream>>>(inputs, idx, wts, ws);
    gemv_kv<<<NBLK, TPB, 0, stream>>>(inputs, ws, ws + WS_P);
    combine<<<1, TPB, 0, stream>>>(ws + WS_P, out);
}